// Round 1
// 2662.580 us; speedup vs baseline: 1.0446x; 1.0446x over previous
//
#include <hip/hip_runtime.h>
#include <math.h>

// Bidirectional 10-layer tanh RNN, T=512 B=64 H=100, + sigmoid head.
// Layers strictly sequential (bidir dependency). Per layer:
//   1) ingemm_kernel: z[dir][m][h] = In[m][:] . W[dir*100+h][:] + bias   (parallel GEMM)
//   2) scan_kernel:   128 blocks = 2 dirs x 64 batch independent recurrence chains
// Final: outproj_kernel (wave-per-row dot200 + sigmoid).
//
// R1: scan_kernel uses raw s_barrier + lgkmcnt(0) instead of __syncthreads()
// (which drains vmcnt(0) every step, putting the full z-load L3 round trip on
// the 512-step critical path), plus a 4-deep statically-indexed z prefetch
// ring so global loads have ~4 steps of latency cover.

#define T_LEN 512
#define BATCH 64
#define HID   100
#define M_TOT (T_LEN * BATCH)   // 32768

// ---------------- input GEMM ----------------
// Z[m][n] = sum_k In[m][k]*W[n][k] + bih[n]+bhh[n], n in [0,200)
// stored z[dir][m][h], dir = n/100, h = n%100
__global__ __launch_bounds__(256) void ingemm_kernel(
    const float* __restrict__ In, const float* __restrict__ W,
    const float* __restrict__ bih, const float* __restrict__ bhh,
    float* __restrict__ z, int K)
{
    __shared__ float As[16][68];
    __shared__ float Bs[16][68];
    const int tid = threadIdx.x;
    const int m0 = blockIdx.x * 64;
    const int n0 = blockIdx.y * 64;
    const int tx = tid & 15, ty = tid >> 4;
    const int lm = tid >> 2;          // 0..63
    const int lk = (tid & 3) << 2;    // 0,4,8,12

    float acc[4][4];
    #pragma unroll
    for (int i = 0; i < 4; ++i)
        #pragma unroll
        for (int j = 0; j < 4; ++j) acc[i][j] = 0.f;

    for (int k0 = 0; k0 < K; k0 += 16) {
        float4 av = make_float4(0.f,0.f,0.f,0.f);
        float4 bv = make_float4(0.f,0.f,0.f,0.f);
        if (k0 + lk < K)   // K%4==0 so a 4-chunk is fully in or out
            av = *(const float4*)(In + (size_t)(m0 + lm) * K + k0 + lk);
        const int nrow = n0 + lm;
        if (nrow < 200 && k0 + lk < K)
            bv = *(const float4*)(W + (size_t)nrow * K + k0 + lk);
        As[lk+0][lm]=av.x; As[lk+1][lm]=av.y; As[lk+2][lm]=av.z; As[lk+3][lm]=av.w;
        Bs[lk+0][lm]=bv.x; Bs[lk+1][lm]=bv.y; Bs[lk+2][lm]=bv.z; Bs[lk+3][lm]=bv.w;
        __syncthreads();
        #pragma unroll
        for (int kk = 0; kk < 16; ++kk) {
            float4 a4 = *(const float4*)&As[kk][ty << 2];
            float4 b4 = *(const float4*)&Bs[kk][tx << 2];
            float a[4] = {a4.x, a4.y, a4.z, a4.w};
            float b[4] = {b4.x, b4.y, b4.z, b4.w};
            #pragma unroll
            for (int i = 0; i < 4; ++i)
                #pragma unroll
                for (int j = 0; j < 4; ++j)
                    acc[i][j] += a[i] * b[j];
        }
        __syncthreads();
    }
    #pragma unroll
    for (int i = 0; i < 4; ++i) {
        const int m = m0 + (ty << 2) + i;
        #pragma unroll
        for (int j = 0; j < 4; ++j) {
            const int n = n0 + (tx << 2) + j;
            if (n < 200) {
                const int dir = (n >= 100) ? 1 : 0;
                const int h = n - dir * 100;
                z[(size_t)dir * M_TOT * HID + (size_t)m * HID + h] =
                    acc[i][j] + bih[n] + bhh[n];
            }
        }
    }
}

// ---------------- recurrent scan ----------------
// One block per (dir, batch) chain. 256 threads: j = tid>>1 (output, <100 active),
// half = tid&1 (k-split). Whh rows live in registers; h double-buffered in LDS.
// Raw s_barrier (NOT __syncthreads) so global z-loads / out-stores stay in
// flight across steps; only lgkmcnt(0) is drained (h ds_write visibility).
__global__ __launch_bounds__(256) void scan_kernel(
    const float* __restrict__ z,    // [2][M][HID]
    const float* __restrict__ Whh,  // [2][HID][HID] for this layer
    float* __restrict__ out)        // [M][200]
{
    const int dir = blockIdx.x >> 6;
    const int b   = blockIdx.x & 63;
    const int tid = threadIdx.x;
    const int j    = tid >> 1;       // 0..127 (active < 100)
    const int half = tid & 1;
    const int kbase = half * 48;     // half0: k 0..51 (w[50..51]=0), half1: k 48..99 (w[0..1]=0)

    __shared__ float h_lds[2][112];
    for (int i = tid; i < 224; i += 256) (&h_lds[0][0])[i] = 0.f;

    float w[52];
    #pragma unroll
    for (int i = 0; i < 52; ++i) w[i] = 0.f;
    if (j < HID) {
        const float* wr = Whh + ((size_t)dir * HID + j) * HID;
        if (half == 0) {
            for (int i = 0; i < 50; ++i) w[i] = wr[i];
        } else {
            for (int i = 2; i < 52; ++i) w[i] = wr[48 + i];
        }
    }
    __syncthreads();   // once, before the hot loop: h_lds zero-init visible

    const int jj = (j < HID) ? j : 0;
    const float* zb = z + (size_t)dir * M_TOT * HID + (size_t)b * HID + jj;
    float* ob = out + (size_t)b * 200 + dir * HID + j;

    const int t0 = dir ? (T_LEN - 1) : 0;
    const ptrdiff_t zstep = dir ? -(ptrdiff_t)(BATCH * HID) : (ptrdiff_t)(BATCH * HID);
    const ptrdiff_t ostep = dir ? -(ptrdiff_t)(BATCH * 200) : (ptrdiff_t)(BATCH * 200);
    const ptrdiff_t zstep2 = 2 * zstep, zstep3 = 3 * zstep, zstep4 = 4 * zstep;

    const float* zp = zb + (ptrdiff_t)t0 * (BATCH * HID);
    float*       op = ob + (ptrdiff_t)t0 * (BATCH * 200);

    // 4-deep prefetch ring, statically indexed (named regs, manual unroll-4)
    float zr0 = zp[0];
    float zr1 = zp[zstep];
    float zr2 = zp[zstep2];
    float zr3 = zp[zstep3];
    const float* zpf = zp + zstep4;   // points at step s+4's z

    int cur = 0;

#define RNN_STEP(ZREG, DO_PF, PFOFF)                                    \
  do {                                                                  \
    const float zin = ZREG;                                             \
    if (DO_PF) ZREG = *(zpf + (PFOFF));   /* fire-and-forget prefetch */\
    const float4* hp = (const float4*)&h_lds[cur][kbase];               \
    float a0 = 0.f, a1 = 0.f, a2 = 0.f, a3 = 0.f;                       \
    _Pragma("unroll")                                                   \
    for (int q = 0; q < 13; ++q) {                                      \
      float4 hv = hp[q];                                                \
      a0 += w[4*q + 0] * hv.x;                                          \
      a1 += w[4*q + 1] * hv.y;                                          \
      a2 += w[4*q + 2] * hv.z;                                          \
      a3 += w[4*q + 3] * hv.w;                                          \
    }                                                                   \
    float accv = (a0 + a1) + (a2 + a3);                                 \
    float tot = accv + __shfl_xor(accv, 1);                             \
    float xin = zin + tot;                                              \
    float ax = fabsf(xin);                                              \
    float e = __expf(2.f * ax);                                         \
    float r = 1.f - 2.f / (e + 1.f);                                    \
    float val = copysignf(r, xin);                                      \
    if (half == 0 && j < HID) {                                         \
      h_lds[cur ^ 1][j] = val;                                          \
      *op = val;                                                        \
    }                                                                   \
    op += ostep;                                                        \
    asm volatile("s_waitcnt lgkmcnt(0)" ::: "memory");                  \
    __builtin_amdgcn_sched_barrier(0);                                  \
    __builtin_amdgcn_s_barrier();                                       \
    __builtin_amdgcn_sched_barrier(0);                                  \
    cur ^= 1;                                                           \
  } while (0)

    // main: 127 groups of 4 steps with prefetch of steps s+4..s+7
    for (int g = 0; g < (T_LEN / 4) - 1; ++g) {
        RNN_STEP(zr0, 1, 0);
        RNN_STEP(zr1, 1, zstep);
        RNN_STEP(zr2, 1, zstep2);
        RNN_STEP(zr3, 1, zstep3);
        zpf += zstep4;
    }
    // tail: last 4 steps, no prefetch
    RNN_STEP(zr0, 0, 0);
    RNN_STEP(zr1, 0, 0);
    RNN_STEP(zr2, 0, 0);
    RNN_STEP(zr3, 0, 0);

#undef RNN_STEP
}

// ---------------- output projection ----------------
__global__ __launch_bounds__(256) void outproj_kernel(
    const float* __restrict__ h, const float* __restrict__ Wout,
    const float* __restrict__ bout, float* __restrict__ y)
{
    const int gid = blockIdx.x * 256 + threadIdx.x;
    const int wid = gid >> 6;
    const int lane = threadIdx.x & 63;
    if (wid >= M_TOT) return;
    const float* row = h + (size_t)wid * 200;
    float acc = 0.f;
    for (int k = lane; k < 200; k += 64) acc += row[k] * Wout[k];
    #pragma unroll
    for (int off = 32; off > 0; off >>= 1) acc += __shfl_xor(acc, off);
    if (lane == 0) y[wid] = 1.f / (1.f + __expf(-(acc + bout[0])));
}

extern "C" void kernel_launch(void* const* d_in, const int* in_sizes, int n_in,
                              void* d_out, int out_size, void* d_ws, size_t ws_size,
                              hipStream_t stream)
{
    const float* x     = (const float*)d_in[0];
    const float* W_ih0 = (const float*)d_in[1];
    const float* W_ih  = (const float*)d_in[2];
    const float* W_hh  = (const float*)d_in[3];
    const float* b_ih  = (const float*)d_in[4];
    const float* b_hh  = (const float*)d_in[5];
    const float* W_out = (const float*)d_in[6];
    const float* b_out = (const float*)d_in[7];
    float* y = (float*)d_out;

    float* z    = (float*)d_ws;                          // 2*M*100 floats
    float* buf0 = z + (size_t)2 * M_TOT * HID;           // M*200
    float* buf1 = buf0 + (size_t)M_TOT * 200;            // M*200

    for (int l = 0; l < 10; ++l) {
        const float* In = (l == 0) ? x : ((l & 1) ? buf0 : buf1);
        float* Out      = (l & 1) ? buf1 : buf0;
        const int K     = (l == 0) ? 100 : 200;
        const float* W  = (l == 0) ? W_ih0 : (W_ih + (size_t)(l - 1) * 2 * 100 * 200);
        ingemm_kernel<<<dim3(M_TOT / 64, 4), 256, 0, stream>>>(
            In, W, b_ih + l * 200, b_hh + l * 200, z, K);
        scan_kernel<<<128, 256, 0, stream>>>(
            z, W_hh + (size_t)l * 2 * HID * HID, Out);
    }
    outproj_kernel<<<M_TOT / 4, 256, 0, stream>>>(buf1, W_out, b_out, y);
}